// Round 1
// baseline (2684.690 us; speedup 1.0000x reference)
//
#include <hip/hip_runtime.h>
#include <cstddef>

// SNN: 4-layer LIF net, T=200 sequential steps, batch 4096.
// R6: counters showed TCC-fetch-BW-bound: dur == 8.04 GB / ~3.5 TB/s on every
// dispatch, MfmaUtil 10%, VALUBusy 10%. Compulsory traffic is only ~0.27 GB;
// the 8 GB is L2 thrash seeded by the x path: nontemporal scattered 16B f4
// loads (16B used / 64B line, no retention) fill each XCD L2 at ~capacity/step,
// so the 622 KB streamed-lo hot set can't survive between (skewed) blocks and
// is re-fetched ~14x/step. Fixes:
//  (1) x staging goes 8-phase (stage 8 steps per event; 200%8==0): each (m,i)
//      consumes 32B of its 64B line in two adjacent f4s, the other 32B one
//      group later from a now-quiet L2. NT hint removed so lines retain.
//  (2) W1hi moves from LDS to 12 pinned VGPRs/lane (each wave only reads its
//      own 16 rows), paying for the larger xA buffer. W1lo stays in LDS at
//      the proven 104 stride. LDS: 53,248 + 53,248 + 25,344 = 131,840 B.
//  Streams, prefetch order, barriers, layer 2-4 code unchanged.
// Numerics bitwise identical to R5 (absmax 0): MFMA inputs/order unchanged.
//
// ws layout (_Float16 units): W1hi[256*96] W1lo[256*96] W2hi[256*256]
// W2lo[..] W3hi[..] W3lo[..]  -> 622,592 bytes.

#define BATCH 4096
#define TSTEPS 200
#define NIN 80
#define KP 96
#define NH 256
#define XPAD 104
#define SPAD 264
#define WP1 104   // W1lo LDS row stride: 52 words -> 2-way max on b128

#define W1HI 0
#define W1LO 24576
#define W2HI 49152
#define W2LO 114688
#define W3HI 180224
#define W3LO 245760

#define LO_SCALE 2048.0f
#define LO_INV 4.8828125e-4f

typedef _Float16 h8 __attribute__((ext_vector_type(8)));
typedef float f4 __attribute__((ext_vector_type(4)));

// LDS-only barrier: wait lgkmcnt(0), do NOT drain vmcnt.
// simm16 0xC07F: vmcnt=63 (no wait), expcnt=7 (no wait), lgkmcnt=0.
__device__ __forceinline__ void lds_barrier() {
  __builtin_amdgcn_s_waitcnt(0xC07F);
  __builtin_amdgcn_s_barrier();
}

// Register pin: opaque asm output — cannot be rematerialized or sunk.
__device__ __forceinline__ void pin4(f4& v) { asm volatile("" : "+v"(v)); }
__device__ __forceinline__ void pinh(h8& v) { asm volatile("" : "+v"(v)); }

__global__ __launch_bounds__(256) void prep_kernel(
    const float* __restrict__ W1, const float* __restrict__ W2,
    const float* __restrict__ W3, _Float16* __restrict__ ws) {
  unsigned id = blockIdx.x * 256u + threadIdx.x;
  if (id >= 24576u + 65536u + 65536u) return;
  float v;
  unsigned off;
  _Float16 *hi, *lo;
  if (id < 24576u) {
    unsigned n = id / KP, k = id % KP;
    v = (k < NIN) ? W1[n * NIN + k] : 0.0f;
    hi = ws + W1HI; lo = ws + W1LO; off = id;
  } else if (id < 90112u) {
    off = id - 24576u; v = W2[off];
    hi = ws + W2HI; lo = ws + W2LO;
  } else {
    off = id - 90112u; v = W3[off];
    hi = ws + W3HI; lo = ws + W3LO;
  }
  _Float16 h = (_Float16)v;
  float r = (v - (float)h) * LO_SCALE;
  hi[off] = h;
  lo[off] = (_Float16)r;
}

__global__ __attribute__((amdgpu_waves_per_eu(4, 4)))
__launch_bounds__(1024) void snn_kernel(
    const float* __restrict__ x,
    const float* __restrict__ b1, const float* __restrict__ b2,
    const float* __restrict__ b3, const float* __restrict__ W4,
    const float* __restrict__ b4, const _Float16* __restrict__ ws,
    float* __restrict__ out) {
  // LDS: W1lo 53,248 + xA(8-phase) 53,248 + S 25,344 = 131,840 B.
  __shared__ alignas(16) _Float16 Wl1[256][WP1];
  __shared__ alignas(16) _Float16 xAhi[8][16][XPAD];
  __shared__ alignas(16) _Float16 xAlo[8][16][XPAD];
  __shared__ alignas(16) _Float16 S1[16][SPAD];
  __shared__ alignas(16) _Float16 S2[16][SPAD];
  __shared__ alignas(16) _Float16 S3[16][SPAD];

  const int tid = threadIdx.x;
  const int wave = tid >> 6;
  const int lane = tid & 63;
  const int n16 = lane & 15;
  const int kg = lane >> 4;
  const int wb = blockIdx.x << 4;
  const int nn = (wave << 4) + n16;

  // One-time W1lo -> LDS (48 KB from L2; 3 iterations/thread).
  for (int c = tid; c < 3072; c += 1024) {
    int row = c / 12, w = c % 12;
    *(h8*)&Wl1[row][w * 8] = *(const h8*)(ws + W1LO + row * KP + w * 8);
  }

  // W1hi in registers: each wave only ever reads its own rows nn (12 VGPRs).
  h8 w1h[3];
  {
    const _Float16* w1p = ws + W1HI + nn * KP;
#pragma unroll
    for (int kt = 0; kt < 3; ++kt)
      w1h[kt] = *(const h8*)(w1p + kt * 32 + kg * 8);
#pragma unroll
    for (int kt = 0; kt < 3; ++kt) pinh(w1h[kt]);
  }

  const _Float16* w2l = ws + W2LO + nn * NH;
  const _Float16* w3l = ws + W3LO + nn * NH;

  const float bb1 = b1[nn], bb2 = b2[nn], bb3 = b3[nn];

  // Register-resident hi planes of W2/W3 (64 VGPRs), pinned.
  f4 w2hi_f[8], w3hi_f[8];
  {
    const float* w2h = (const float*)(ws + W2HI + nn * NH);
    const float* w3h = (const float*)(ws + W3HI + nn * NH);
#pragma unroll
    for (int kt = 0; kt < 8; ++kt) {
      w2hi_f[kt] = *(const f4*)(w2h + kt * 16 + kg * 4);
      w3hi_f[kt] = *(const f4*)(w3h + kt * 16 + kg * 4);
    }
#pragma unroll
    for (int kt = 0; kt < 8; ++kt) {
      pin4(w2hi_f[kt]);
      pin4(w3hi_f[kt]);
    }
  }

  // Layer 4 lane roles.
  const int j4 = lane >> 5;
  const int ks4 = (lane & 31) << 3;
  const float* w4p = W4 + j4 * NH + ks4;
  const float bb4 = b4[j4];

  float mem1[4] = {0.f, 0.f, 0.f, 0.f};
  float mem2[4] = {0.f, 0.f, 0.f, 0.f};
  float mem3[4] = {0.f, 0.f, 0.f, 0.f};
  float mem4 = 0.f;

  for (int t = 0; t < TSTEPS; ++t) {
    const int ph = t & 7;
    if (ph == 0) {
      // Stage 8 steps of x. Per (m,i): two adjacent f4s = 32 B of one 64 B
      // line (cacheable — no NT), other half consumed next group via L2.
      for (unsigned e = (unsigned)tid; e < 3072u; e += 1024u) {
        unsigned m = e / 192u, r = e % 192u, i = r >> 1, t4 = r & 1u;
        f4 v = {0.f, 0.f, 0.f, 0.f};
        if (i < NIN)
          v = *(const f4*)(x + ((size_t)(wb + m) * NIN + i) * TSTEPS + t +
                           t4 * 4);
#pragma unroll
        for (int s = 0; s < 4; ++s) {
          float f = v[s];
          _Float16 h = (_Float16)f;
          xAhi[t4 * 4 + s][m][i] = h;
          xAlo[t4 * 4 + s][m][i] = (_Float16)((f - (float)h) * LO_SCALE);
        }
      }
      lds_barrier();  // also covers the one-time W1lo LDS fill at t=0
    }

    // ---------------- layer 1 : xA from LDS, W1hi regs, W1lo LDS ----------
    // Prefetch first half of W2lo; it stays outstanding across the S1
    // barrier (lds_barrier leaves vmcnt alone).
    h8 wl2a[4];
#pragma unroll
    for (int q = 0; q < 4; ++q)
      wl2a[q] = *(const h8*)(w2l + q * 32 + kg * 8);

    f4 aH = {0.f, 0.f, 0.f, 0.f};
    f4 aL = {0.f, 0.f, 0.f, 0.f};
#pragma unroll
    for (int kt = 0; kt < 3; ++kt) {
      const int ko = kt * 32 + kg * 8;
      h8 ahi = *(const h8*)&xAhi[ph][n16][ko];
      h8 alo = *(const h8*)&xAlo[ph][n16][ko];
      h8 wl = *(const h8*)&Wl1[nn][ko];
      aH = __builtin_amdgcn_mfma_f32_16x16x32_f16(ahi, w1h[kt], aH, 0, 0, 0);
      aL = __builtin_amdgcn_mfma_f32_16x16x32_f16(alo, w1h[kt], aL, 0, 0, 0);
      aL = __builtin_amdgcn_mfma_f32_16x16x32_f16(ahi, wl, aL, 0, 0, 0);
    }
#pragma unroll
    for (int r = 0; r < 4; ++r) {
      float cur = __fadd_rn(__fadd_rn(aH[r], __fmul_rn(aL[r], LO_INV)), bb1);
      float mo = mem1[r];
      float mn = __fsub_rn(__fadd_rn(__fmul_rn(0.95f, mo), cur),
                           (mo > 1.0f) ? 1.0f : 0.0f);
      mem1[r] = mn;
      S1[kg * 4 + r][nn] = (mn > 1.0f) ? (_Float16)1.0f : (_Float16)0.0f;
    }
    lds_barrier();

    // ---------------- layer 2 : hi resident, lo streamed ----------------
    h8 wl2b[4];
#pragma unroll
    for (int q = 0; q < 4; ++q)
      wl2b[q] = *(const h8*)(w2l + (4 + q) * 32 + kg * 8);

    // Hi phase: register-only MFMAs run while wl2 loads land.
    aH = (f4){0.f, 0.f, 0.f, 0.f};
    aL = (f4){0.f, 0.f, 0.f, 0.f};
#pragma unroll
    for (int kt = 0; kt < 8; ++kt) {
      h8 a = *(const h8*)&S1[n16][kt * 32 + kg * 8];
      aH = __builtin_amdgcn_mfma_f32_16x16x32_f16(
          a, __builtin_bit_cast(h8, w2hi_f[kt]), aH, 0, 0, 0);
    }
#pragma unroll
    for (int q = 0; q < 4; ++q) {
      h8 a = *(const h8*)&S1[n16][q * 32 + kg * 8];
      aL = __builtin_amdgcn_mfma_f32_16x16x32_f16(a, wl2a[q], aL, 0, 0, 0);
    }
    h8 wl3a[4];
#pragma unroll
    for (int q = 0; q < 4; ++q)
      wl3a[q] = *(const h8*)(w3l + q * 32 + kg * 8);
#pragma unroll
    for (int q = 0; q < 4; ++q) {
      h8 a = *(const h8*)&S1[n16][(4 + q) * 32 + kg * 8];
      aL = __builtin_amdgcn_mfma_f32_16x16x32_f16(a, wl2b[q], aL, 0, 0, 0);
    }
#pragma unroll
    for (int r = 0; r < 4; ++r) {
      float cur = __fadd_rn(__fadd_rn(aH[r], __fmul_rn(aL[r], LO_INV)), bb2);
      float mo = mem2[r];
      float mn = __fsub_rn(__fadd_rn(__fmul_rn(0.95f, mo), cur),
                           (mo > 1.0f) ? 1.0f : 0.0f);
      mem2[r] = mn;
      S2[kg * 4 + r][nn] = (mn > 1.0f) ? (_Float16)1.0f : (_Float16)0.0f;
    }
    lds_barrier();

    // ---------------- layer 3 : hi resident, lo streamed ----------------
    h8 wl3b[4];
#pragma unroll
    for (int q = 0; q < 4; ++q)
      wl3b[q] = *(const h8*)(w3l + (4 + q) * 32 + kg * 8);

    aH = (f4){0.f, 0.f, 0.f, 0.f};
    aL = (f4){0.f, 0.f, 0.f, 0.f};
#pragma unroll
    for (int kt = 0; kt < 8; ++kt) {
      h8 a = *(const h8*)&S2[n16][kt * 32 + kg * 8];
      aH = __builtin_amdgcn_mfma_f32_16x16x32_f16(
          a, __builtin_bit_cast(h8, w3hi_f[kt]), aH, 0, 0, 0);
    }
#pragma unroll
    for (int q = 0; q < 4; ++q) {
      h8 a = *(const h8*)&S2[n16][q * 32 + kg * 8];
      aL = __builtin_amdgcn_mfma_f32_16x16x32_f16(a, wl3a[q], aL, 0, 0, 0);
    }
    // Prefetch W4 row (L1-hot): outstanding across the S3 barrier.
    f4 w4a = *(const f4*)(w4p);
    f4 w4b = *(const f4*)(w4p + 4);
#pragma unroll
    for (int q = 0; q < 4; ++q) {
      h8 a = *(const h8*)&S2[n16][(4 + q) * 32 + kg * 8];
      aL = __builtin_amdgcn_mfma_f32_16x16x32_f16(a, wl3b[q], aL, 0, 0, 0);
    }
#pragma unroll
    for (int r = 0; r < 4; ++r) {
      float cur = __fadd_rn(__fadd_rn(aH[r], __fmul_rn(aL[r], LO_INV)), bb3);
      float mo = mem3[r];
      float mn = __fsub_rn(__fadd_rn(__fmul_rn(0.95f, mo), cur),
                           (mo > 1.0f) ? 1.0f : 0.0f);
      mem3[r] = mn;
      S3[kg * 4 + r][nn] = (mn > 1.0f) ? (_Float16)1.0f : (_Float16)0.0f;
    }
    lds_barrier();

    // ---------------- layer 4 : VALU dot + butterfly ----------------
    {
      h8 s = *(const h8*)&S3[wave][ks4];
      float p = 0.0f;
#pragma unroll
      for (int u = 0; u < 4; ++u)
        p = __fadd_rn(p, __fmul_rn((float)s[u], w4a[u]));
#pragma unroll
      for (int u = 0; u < 4; ++u)
        p = __fadd_rn(p, __fmul_rn((float)s[4 + u], w4b[u]));
#pragma unroll
      for (int msk = 1; msk <= 16; msk <<= 1)
        p = __fadd_rn(p, __shfl_xor(p, msk));
      float cur = __fadd_rn(p, bb4);
      float mo = mem4;
      float mn = __fsub_rn(__fadd_rn(__fmul_rn(0.95f, mo), cur),
                           (mo > 1.0f) ? 1.0f : 0.0f);
      mem4 = mn;
      if ((lane & 31) == 0)
        __builtin_nontemporal_store(
            (mn > 1.0f) ? 1.0f : 0.0f,
            out + (size_t)t * (BATCH * 2) + (size_t)(wb + wave) * 2 + j4);
    }
  }
}

extern "C" void kernel_launch(void* const* d_in, const int* in_sizes, int n_in,
                              void* d_out, int out_size, void* d_ws,
                              size_t ws_size, hipStream_t stream) {
  const float* x  = (const float*)d_in[0];
  const float* W1 = (const float*)d_in[1];
  const float* b1 = (const float*)d_in[2];
  const float* W2 = (const float*)d_in[3];
  const float* b2 = (const float*)d_in[4];
  const float* W3 = (const float*)d_in[5];
  const float* b3 = (const float*)d_in[6];
  const float* W4 = (const float*)d_in[7];
  const float* b4 = (const float*)d_in[8];
  float* out = (float*)d_out;
  _Float16* ws = (_Float16*)d_ws;

  hipLaunchKernelGGL(prep_kernel, dim3(608), dim3(256), 0, stream,
                     W1, W2, W3, ws);
  hipLaunchKernelGGL(snn_kernel, dim3(BATCH / 16), dim3(1024), 0, stream,
                     x, b1, b2, b3, W4, b4, ws, out);
}

// Round 3
// 2579.826 us; speedup vs baseline: 1.0406x; 1.0406x over previous
//
#include <hip/hip_runtime.h>
#include <cstddef>

// SNN: 4-layer LIF net, T=200 sequential steps, batch 4096.
// R8 == R7 resubmit (R7 hit an infra container failure, no counters).
// Theory under test: R5/R6 counters showed VGPR_Count=64 with ~86 MB of
// non-output WRITE_SIZE -> the "+v"-pinned weight planes (64+12 VGPRs)
// never fit the arch-VGPR budget; the RA spilled them to scratch, and the
// per-step reloads (scratch set ~11 MB/XCD >> 4 MB L2) are the ~8 GB FETCH
// at 3.6 TB/s that bounds the kernel.
// Fix: pin the resident planes into AGPRs ("+a"). gfx950's unified RF gives
// >=256 regs/lane at any plausible budget; MFMA reads A/B from AGPR
// directly (ISA sec.10), so 76 AGPRs + ~64 arch VGPRs fits spill-free.
// Everything else (streams, barriers, MFMA order) identical to R6 ->
// numerics bitwise identical, absmax 0.
//
// ws layout (_Float16 units): W1hi[256*96] W1lo[256*96] W2hi[256*256]
// W2lo[..] W3hi[..] W3lo[..]  -> 622,592 bytes.

#define BATCH 4096
#define TSTEPS 200
#define NIN 80
#define KP 96
#define NH 256
#define XPAD 104
#define SPAD 264
#define WP1 104   // W1lo LDS row stride: 52 words -> 2-way max on b128

#define W1HI 0
#define W1LO 24576
#define W2HI 49152
#define W2LO 114688
#define W3HI 180224
#define W3LO 245760

#define LO_SCALE 2048.0f
#define LO_INV 4.8828125e-4f

typedef _Float16 h8 __attribute__((ext_vector_type(8)));
typedef float f4 __attribute__((ext_vector_type(4)));

// LDS-only barrier: wait lgkmcnt(0), do NOT drain vmcnt.
// simm16 0xC07F: vmcnt=63 (no wait), expcnt=7 (no wait), lgkmcnt=0.
__device__ __forceinline__ void lds_barrier() {
  __builtin_amdgcn_s_waitcnt(0xC07F);
  __builtin_amdgcn_s_barrier();
}

// AGPR pin: forces the value into accumulator registers (unified RF on
// gfx950). Arch-VGPR budget stays small -> no scratch spill. MFMA consumes
// AGPR operands directly.
__device__ __forceinline__ void pin4(f4& v) { asm volatile("" : "+a"(v)); }
__device__ __forceinline__ void pinh(h8& v) { asm volatile("" : "+a"(v)); }

__global__ __launch_bounds__(256) void prep_kernel(
    const float* __restrict__ W1, const float* __restrict__ W2,
    const float* __restrict__ W3, _Float16* __restrict__ ws) {
  unsigned id = blockIdx.x * 256u + threadIdx.x;
  if (id >= 24576u + 65536u + 65536u) return;
  float v;
  unsigned off;
  _Float16 *hi, *lo;
  if (id < 24576u) {
    unsigned n = id / KP, k = id % KP;
    v = (k < NIN) ? W1[n * NIN + k] : 0.0f;
    hi = ws + W1HI; lo = ws + W1LO; off = id;
  } else if (id < 90112u) {
    off = id - 24576u; v = W2[off];
    hi = ws + W2HI; lo = ws + W2LO;
  } else {
    off = id - 90112u; v = W3[off];
    hi = ws + W3HI; lo = ws + W3LO;
  }
  _Float16 h = (_Float16)v;
  float r = (v - (float)h) * LO_SCALE;
  hi[off] = h;
  lo[off] = (_Float16)r;
}

__global__ __attribute__((amdgpu_waves_per_eu(4, 4)))
__launch_bounds__(1024) void snn_kernel(
    const float* __restrict__ x,
    const float* __restrict__ b1, const float* __restrict__ b2,
    const float* __restrict__ b3, const float* __restrict__ W4,
    const float* __restrict__ b4, const _Float16* __restrict__ ws,
    float* __restrict__ out) {
  // LDS: W1lo 53,248 + xA(8-phase) 53,248 + S 25,344 = 131,840 B.
  __shared__ alignas(16) _Float16 Wl1[256][WP1];
  __shared__ alignas(16) _Float16 xAhi[8][16][XPAD];
  __shared__ alignas(16) _Float16 xAlo[8][16][XPAD];
  __shared__ alignas(16) _Float16 S1[16][SPAD];
  __shared__ alignas(16) _Float16 S2[16][SPAD];
  __shared__ alignas(16) _Float16 S3[16][SPAD];

  const int tid = threadIdx.x;
  const int wave = tid >> 6;
  const int lane = tid & 63;
  const int n16 = lane & 15;
  const int kg = lane >> 4;
  const int wb = blockIdx.x << 4;
  const int nn = (wave << 4) + n16;

  // One-time W1lo -> LDS (48 KB from L2; 3 iterations/thread).
  for (int c = tid; c < 3072; c += 1024) {
    int row = c / 12, w = c % 12;
    *(h8*)&Wl1[row][w * 8] = *(const h8*)(ws + W1LO + row * KP + w * 8);
  }

  // W1hi in AGPRs: each wave only ever reads its own rows nn (12 regs).
  h8 w1h[3];
  {
    const _Float16* w1p = ws + W1HI + nn * KP;
#pragma unroll
    for (int kt = 0; kt < 3; ++kt)
      w1h[kt] = *(const h8*)(w1p + kt * 32 + kg * 8);
#pragma unroll
    for (int kt = 0; kt < 3; ++kt) pinh(w1h[kt]);
  }

  const _Float16* w2l = ws + W2LO + nn * NH;
  const _Float16* w3l = ws + W3LO + nn * NH;

  const float bb1 = b1[nn], bb2 = b2[nn], bb3 = b3[nn];

  // Resident hi planes of W2/W3 (64 regs), pinned into AGPRs.
  f4 w2hi_f[8], w3hi_f[8];
  {
    const float* w2h = (const float*)(ws + W2HI + nn * NH);
    const float* w3h = (const float*)(ws + W3HI + nn * NH);
#pragma unroll
    for (int kt = 0; kt < 8; ++kt) {
      w2hi_f[kt] = *(const f4*)(w2h + kt * 16 + kg * 4);
      w3hi_f[kt] = *(const f4*)(w3h + kt * 16 + kg * 4);
    }
#pragma unroll
    for (int kt = 0; kt < 8; ++kt) {
      pin4(w2hi_f[kt]);
      pin4(w3hi_f[kt]);
    }
  }

  // Layer 4 lane roles.
  const int j4 = lane >> 5;
  const int ks4 = (lane & 31) << 3;
  const float* w4p = W4 + j4 * NH + ks4;
  const float bb4 = b4[j4];

  float mem1[4] = {0.f, 0.f, 0.f, 0.f};
  float mem2[4] = {0.f, 0.f, 0.f, 0.f};
  float mem3[4] = {0.f, 0.f, 0.f, 0.f};
  float mem4 = 0.f;

  for (int t = 0; t < TSTEPS; ++t) {
    const int ph = t & 7;
    if (ph == 0) {
      // Stage 8 steps of x. Per (m,i): two adjacent f4s = 32 B of one 64 B
      // line (cacheable), other half consumed next group via L2.
      for (unsigned e = (unsigned)tid; e < 3072u; e += 1024u) {
        unsigned m = e / 192u, r = e % 192u, i = r >> 1, t4 = r & 1u;
        f4 v = {0.f, 0.f, 0.f, 0.f};
        if (i < NIN)
          v = *(const f4*)(x + ((size_t)(wb + m) * NIN + i) * TSTEPS + t +
                           t4 * 4);
#pragma unroll
        for (int s = 0; s < 4; ++s) {
          float f = v[s];
          _Float16 h = (_Float16)f;
          xAhi[t4 * 4 + s][m][i] = h;
          xAlo[t4 * 4 + s][m][i] = (_Float16)((f - (float)h) * LO_SCALE);
        }
      }
      lds_barrier();  // also covers the one-time W1lo LDS fill at t=0
    }

    // ---------------- layer 1 : xA from LDS, W1hi AGPR, W1lo LDS ----------
    // Prefetch first half of W2lo; it stays outstanding across the S1
    // barrier (lds_barrier leaves vmcnt alone).
    h8 wl2a[4];
#pragma unroll
    for (int q = 0; q < 4; ++q)
      wl2a[q] = *(const h8*)(w2l + q * 32 + kg * 8);

    f4 aH = {0.f, 0.f, 0.f, 0.f};
    f4 aL = {0.f, 0.f, 0.f, 0.f};
#pragma unroll
    for (int kt = 0; kt < 3; ++kt) {
      const int ko = kt * 32 + kg * 8;
      h8 ahi = *(const h8*)&xAhi[ph][n16][ko];
      h8 alo = *(const h8*)&xAlo[ph][n16][ko];
      h8 wl = *(const h8*)&Wl1[nn][ko];
      aH = __builtin_amdgcn_mfma_f32_16x16x32_f16(ahi, w1h[kt], aH, 0, 0, 0);
      aL = __builtin_amdgcn_mfma_f32_16x16x32_f16(alo, w1h[kt], aL, 0, 0, 0);
      aL = __builtin_amdgcn_mfma_f32_16x16x32_f16(ahi, wl, aL, 0, 0, 0);
    }
#pragma unroll
    for (int r = 0; r < 4; ++r) {
      float cur = __fadd_rn(__fadd_rn(aH[r], __fmul_rn(aL[r], LO_INV)), bb1);
      float mo = mem1[r];
      float mn = __fsub_rn(__fadd_rn(__fmul_rn(0.95f, mo), cur),
                           (mo > 1.0f) ? 1.0f : 0.0f);
      mem1[r] = mn;
      S1[kg * 4 + r][nn] = (mn > 1.0f) ? (_Float16)1.0f : (_Float16)0.0f;
    }
    lds_barrier();

    // ---------------- layer 2 : hi resident, lo streamed ----------------
    h8 wl2b[4];
#pragma unroll
    for (int q = 0; q < 4; ++q)
      wl2b[q] = *(const h8*)(w2l + (4 + q) * 32 + kg * 8);

    // Hi phase: register-only MFMAs run while wl2 loads land.
    aH = (f4){0.f, 0.f, 0.f, 0.f};
    aL = (f4){0.f, 0.f, 0.f, 0.f};
#pragma unroll
    for (int kt = 0; kt < 8; ++kt) {
      h8 a = *(const h8*)&S1[n16][kt * 32 + kg * 8];
      aH = __builtin_amdgcn_mfma_f32_16x16x32_f16(
          a, __builtin_bit_cast(h8, w2hi_f[kt]), aH, 0, 0, 0);
    }
#pragma unroll
    for (int q = 0; q < 4; ++q) {
      h8 a = *(const h8*)&S1[n16][q * 32 + kg * 8];
      aL = __builtin_amdgcn_mfma_f32_16x16x32_f16(a, wl2a[q], aL, 0, 0, 0);
    }
    h8 wl3a[4];
#pragma unroll
    for (int q = 0; q < 4; ++q)
      wl3a[q] = *(const h8*)(w3l + q * 32 + kg * 8);
#pragma unroll
    for (int q = 0; q < 4; ++q) {
      h8 a = *(const h8*)&S1[n16][(4 + q) * 32 + kg * 8];
      aL = __builtin_amdgcn_mfma_f32_16x16x32_f16(a, wl2b[q], aL, 0, 0, 0);
    }
#pragma unroll
    for (int r = 0; r < 4; ++r) {
      float cur = __fadd_rn(__fadd_rn(aH[r], __fmul_rn(aL[r], LO_INV)), bb2);
      float mo = mem2[r];
      float mn = __fsub_rn(__fadd_rn(__fmul_rn(0.95f, mo), cur),
                           (mo > 1.0f) ? 1.0f : 0.0f);
      mem2[r] = mn;
      S2[kg * 4 + r][nn] = (mn > 1.0f) ? (_Float16)1.0f : (_Float16)0.0f;
    }
    lds_barrier();

    // ---------------- layer 3 : hi resident, lo streamed ----------------
    h8 wl3b[4];
#pragma unroll
    for (int q = 0; q < 4; ++q)
      wl3b[q] = *(const h8*)(w3l + (4 + q) * 32 + kg * 8);

    aH = (f4){0.f, 0.f, 0.f, 0.f};
    aL = (f4){0.f, 0.f, 0.f, 0.f};
#pragma unroll
    for (int kt = 0; kt < 8; ++kt) {
      h8 a = *(const h8*)&S2[n16][kt * 32 + kg * 8];
      aH = __builtin_amdgcn_mfma_f32_16x16x32_f16(
          a, __builtin_bit_cast(h8, w3hi_f[kt]), aH, 0, 0, 0);
    }
#pragma unroll
    for (int q = 0; q < 4; ++q) {
      h8 a = *(const h8*)&S2[n16][q * 32 + kg * 8];
      aL = __builtin_amdgcn_mfma_f32_16x16x32_f16(a, wl3a[q], aL, 0, 0, 0);
    }
    // Prefetch W4 row (L1-hot): outstanding across the S3 barrier.
    f4 w4a = *(const f4*)(w4p);
    f4 w4b = *(const f4*)(w4p + 4);
#pragma unroll
    for (int q = 0; q < 4; ++q) {
      h8 a = *(const h8*)&S2[n16][(4 + q) * 32 + kg * 8];
      aL = __builtin_amdgcn_mfma_f32_16x16x32_f16(a, wl3b[q], aL, 0, 0, 0);
    }
#pragma unroll
    for (int r = 0; r < 4; ++r) {
      float cur = __fadd_rn(__fadd_rn(aH[r], __fmul_rn(aL[r], LO_INV)), bb3);
      float mo = mem3[r];
      float mn = __fsub_rn(__fadd_rn(__fmul_rn(0.95f, mo), cur),
                           (mo > 1.0f) ? 1.0f : 0.0f);
      mem3[r] = mn;
      S3[kg * 4 + r][nn] = (mn > 1.0f) ? (_Float16)1.0f : (_Float16)0.0f;
    }
    lds_barrier();

    // ---------------- layer 4 : VALU dot + butterfly ----------------
    {
      h8 s = *(const h8*)&S3[wave][ks4];
      float p = 0.0f;
#pragma unroll
      for (int u = 0; u < 4; ++u)
        p = __fadd_rn(p, __fmul_rn((float)s[u], w4a[u]));
#pragma unroll
      for (int u = 0; u < 4; ++u)
        p = __fadd_rn(p, __fmul_rn((float)s[4 + u], w4b[u]));
#pragma unroll
      for (int msk = 1; msk <= 16; msk <<= 1)
        p = __fadd_rn(p, __shfl_xor(p, msk));
      float cur = __fadd_rn(p, bb4);
      float mo = mem4;
      float mn = __fsub_rn(__fadd_rn(__fmul_rn(0.95f, mo), cur),
                           (mo > 1.0f) ? 1.0f : 0.0f);
      mem4 = mn;
      if ((lane & 31) == 0)
        __builtin_nontemporal_store(
            (mn > 1.0f) ? 1.0f : 0.0f,
            out + (size_t)t * (BATCH * 2) + (size_t)(wb + wave) * 2 + j4);
    }
  }
}

extern "C" void kernel_launch(void* const* d_in, const int* in_sizes, int n_in,
                              void* d_out, int out_size, void* d_ws,
                              size_t ws_size, hipStream_t stream) {
  const float* x  = (const float*)d_in[0];
  const float* W1 = (const float*)d_in[1];
  const float* b1 = (const float*)d_in[2];
  const float* W2 = (const float*)d_in[3];
  const float* b2 = (const float*)d_in[4];
  const float* W3 = (const float*)d_in[5];
  const float* b3 = (const float*)d_in[6];
  const float* W4 = (const float*)d_in[7];
  const float* b4 = (const float*)d_in[8];
  float* out = (float*)d_out;
  _Float16* ws = (_Float16*)d_ws;

  hipLaunchKernelGGL(prep_kernel, dim3(608), dim3(256), 0, stream,
                     W1, W2, W3, ws);
  hipLaunchKernelGGL(snn_kernel, dim3(BATCH / 16), dim3(1024), 0, stream,
                     x, b1, b2, b3, W4, b4, ws, out);
}